// Round 13
// baseline (166.553 us; speedup 1.0000x reference)
//
#include <hip/hip_runtime.h>

#define N_NODES 50000
#define N_PANELS 3125            // 50000 / 16 exactly
#define N_EDGES 300000
#define EPS_F 1e-12f
#define DEGB 64                           // compact deg blocks (grid-stride)
#define WB 96                             // wsplit blocks
#define AB (N_NODES * 32 / 256)           // 6250 asplit blocks
#define FILLB 128                         // compact fill blocks (grid-stride)
#define GB 512                            // gemm/fused grid
#define SCAN_NB ((N_NODES + 255) / 256)   // 196
#define ZBYTES (N_NODES * 12)             // pk_out(4) + pk_in(4) + cur(4)

typedef _Float16 f16x8 __attribute__((ext_vector_type(8)));
typedef float f32x4 __attribute__((ext_vector_type(4)));

static __device__ inline f32x4 mfma_f16(f16x8 a, f16x8 b, f32x4 c) {
    return __builtin_amdgcn_mfma_f32_16x16x32_f16(a, b, c, 0, 0, 0);
}

// fragment-ready swizzled layout for a [R][256] f16 matrix:
// element (row, k) at ((row>>4)*8 + (k>>5))*512 + ((k>>3)&3)*128 + (row&15)*8 + (k&7)
static __device__ inline size_t swz(int row, int l) {
    return ((size_t)(row >> 4) * 8 + (l >> 2)) * 512 + (size_t)((l & 3) * 128 + (row & 15) * 8);
}

// ---------------------------------------------------------------------------
// Workspace zero-init
// ---------------------------------------------------------------------------

__global__ __launch_bounds__(256) void zero_kernel(int4* __restrict__ p, int n16) {
    int i = blockIdx.x * 256 + threadIdx.x;
    if (i < n16) p[i] = make_int4(0, 0, 0, 0);
}

// ---------------------------------------------------------------------------
// P1: deg (u32 packed fixed-point atomics, compact) ∥ wsplit ∥ asplit
//   pk_in[d]  += (1<<24) | (w * 2^18)   (cnt in bits 24..31, sum in 0..23)
//   pk_out[s] += (w * 2^18)
// deg<=~35, sum(w)<64 -> no overflow/carry. Quantization 2^-18 (negligible).
// ---------------------------------------------------------------------------

__global__ __launch_bounds__(256) void p1_kernel(const int* __restrict__ ei,
                                                 const float* __restrict__ ew,
                                                 unsigned* __restrict__ pk_out,
                                                 unsigned* __restrict__ pk_in,
                                                 const float* __restrict__ W6,
                                                 const float* __restrict__ W7,
                                                 const float* __restrict__ Wp,
                                                 _Float16* __restrict__ Bsw,
                                                 const float* __restrict__ h5,
                                                 _Float16* __restrict__ Asw) {
    int b = blockIdx.x;
    if (b < DEGB) {
        for (int e = b * 256 + (int)threadIdx.x; e < N_EDGES; e += DEGB * 256) {
            int s = ei[e];
            int d = ei[N_EDGES + e];
            unsigned wfx = (unsigned)(ew[e] * 262144.0f);   // 2^18
            atomicAdd(&pk_out[s], wfx);
            atomicAdd(&pk_in[d], (1u << 24) | wfx);
        }
    } else if (b < DEGB + WB) {
        int bb = b - DEGB;                // 0..95
        int wsel = bb >> 5;               // 0..2
        const float* W = (wsel == 0) ? W6 : (wsel == 1) ? W7 : Wp;
        int id = (bb & 31) * 256 + threadIdx.x;   // 0..8191
        int n = id >> 5, l = id & 31;
        f16x8 o;
#pragma unroll
        for (int j = 0; j < 8; ++j)
            o[j] = (_Float16)W[(l * 8 + j) * 256 + n];
        *(f16x8*)&Bsw[(size_t)wsel * 65536 + swz(n, l)] = o;
    } else {
        int tid = (b - DEGB - WB) * 256 + threadIdx.x;   // 0 .. 1,600,000 exact
        int row = tid >> 5, l = tid & 31;
        const float* p = &h5[(size_t)row * 256 + l * 8];
        float4 v0 = *(const float4*)p;
        float4 v1 = *(const float4*)(p + 4);
        f16x8 o;
        o[0] = (_Float16)v0.x; o[1] = (_Float16)v0.y;
        o[2] = (_Float16)v0.z; o[3] = (_Float16)v0.w;
        o[4] = (_Float16)v1.x; o[5] = (_Float16)v1.y;
        o[6] = (_Float16)v1.z; o[7] = (_Float16)v1.w;
        *(f16x8*)&Asw[swz(row, l)] = o;
    }
}

// --- scan: per-block reduce, then fused (partial-scan + local scan) ---------

__global__ __launch_bounds__(256) void scan1_kernel(const unsigned* __restrict__ pk_in,
                                                    const unsigned* __restrict__ pk_out,
                                                    float* __restrict__ deg_in,
                                                    float* __restrict__ deg_out,
                                                    int* __restrict__ partial) {
    __shared__ int sh[256];
    int i = blockIdx.x * 256 + threadIdx.x;
    int c = 0;
    if (i < N_NODES) {
        unsigned p = pk_in[i];
        c = (int)(p >> 24);
        deg_in[i] = (float)(p & 0xFFFFFFu) * 0x1p-18f;
        deg_out[i] = (float)pk_out[i] * 0x1p-18f;
    }
    sh[threadIdx.x] = c;
    __syncthreads();
    for (int off = 128; off > 0; off >>= 1) {
        if (threadIdx.x < (unsigned)off) sh[threadIdx.x] += sh[threadIdx.x + off];
        __syncthreads();
    }
    if (threadIdx.x == 0) partial[blockIdx.x] = sh[0];
}

// fused scan2+scan3: every block redundantly scans the 196 partials (trivial)
__global__ __launch_bounds__(256) void scan23_kernel(const unsigned* __restrict__ pk_in,
                                                     const int* __restrict__ partial,
                                                     int* __restrict__ row_ptr) {
    __shared__ int ps[256];
    __shared__ int sh[256];
    int t = threadIdx.x;
    int pv = (t < SCAN_NB) ? partial[t] : 0;
    ps[t] = pv;
    __syncthreads();
    for (int off = 1; off < 256; off <<= 1) {
        int x = (t >= off) ? ps[t - off] : 0;
        __syncthreads();
        ps[t] += x;
        __syncthreads();
    }
    int incl = ps[t];
    __syncthreads();
    ps[t] = incl - pv;    // exclusive prefix of partials
    __syncthreads();
    const int boff = ps[blockIdx.x];

    int i = blockIdx.x * 256 + t;
    int v = (i < N_NODES) ? (int)(pk_in[i] >> 24) : 0;
    sh[t] = v;
    __syncthreads();
    for (int off = 1; off < 256; off <<= 1) {
        int x = (t >= off) ? sh[t - off] : 0;
        __syncthreads();
        sh[t] += x;
        __syncthreads();
    }
    if (i < N_NODES) row_ptr[i] = sh[t] - v + boff;
    if (i == 0) row_ptr[N_NODES] = N_EDGES;
}

// ---------------------------------------------------------------------------
// P2: fill (compact grid-strided) ∥ gemm layer-1 (swizzled A -> row-major xt)
// ---------------------------------------------------------------------------

__global__ __launch_bounds__(256) void p2_kernel(const int* __restrict__ ei,
                                                 const float* __restrict__ ew,
                                                 const float* __restrict__ deg_out,
                                                 const float* __restrict__ deg_in,
                                                 const int* __restrict__ row_ptr,
                                                 int* __restrict__ cur,
                                                 int2* __restrict__ csr,
                                                 const _Float16* __restrict__ Asw,
                                                 const _Float16* __restrict__ Bsw,
                                                 _Float16* __restrict__ xt) {
    __shared__ __align__(16) _Float16 ebuf[4][16 * 72];

    if (blockIdx.x < FILLB) {
        for (int e = blockIdx.x * 256 + (int)threadIdx.x; e < N_EDGES; e += FILLB * 256) {
            int s = ei[e];
            int d = ei[N_EDGES + e];
            float nm = ew[e] * rsqrtf(deg_out[s] * deg_in[d] + EPS_F);
            int pos = atomicAdd(&cur[d], 1);
            csr[row_ptr[d] + pos] = make_int2(s, __float_as_int(nm));
        }
        return;
    }

    const int t = threadIdx.x;
    const int w = t >> 6, lane = t & 63;

    f16x8 bf[4][8];
#pragma unroll
    for (int cp4 = 0; cp4 < 4; ++cp4)
#pragma unroll
        for (int kb = 0; kb < 8; ++kb)
            bf[cp4][kb] = *(const f16x8*)&Bsw[(size_t)((w * 4 + cp4) * 8 + kb) * 512 + lane * 8];

    for (int p = blockIdx.x - FILLB; p < N_PANELS; p += GB) {
        const _Float16* abase = &Asw[(size_t)p * 4096 + lane * 8];
        f16x8 af[8];
#pragma unroll
        for (int kb = 0; kb < 8; ++kb)
            af[kb] = *(const f16x8*)&abase[kb * 512];

        f32x4 acc[4];
#pragma unroll
        for (int cp4 = 0; cp4 < 4; ++cp4) acc[cp4] = (f32x4){0.f, 0.f, 0.f, 0.f};
#pragma unroll
        for (int kb = 0; kb < 8; ++kb)
#pragma unroll
            for (int cp4 = 0; cp4 < 4; ++cp4)
                acc[cp4] = mfma_f16(af[kb], bf[cp4][kb], acc[cp4]);

        // D: row = 4*(lane>>4)+reg, col = lane&15  [m89-verified]
        _Float16* eb = ebuf[w];
        const int rq = 4 * (lane >> 4);
        const int lr = lane & 15;
#pragma unroll
        for (int cp4 = 0; cp4 < 4; ++cp4)
#pragma unroll
            for (int rr = 0; rr < 4; ++rr)
                eb[(rq + rr) * 72 + cp4 * 16 + lr] = (_Float16)acc[cp4][rr];
#pragma unroll
        for (int it = 0; it < 2; ++it) {
            int rl = it * 8 + (lane >> 3);
            f16x8 v = *(const f16x8*)&eb[rl * 72 + (lane & 7) * 8];
            *(f16x8*)&xt[(size_t)(p * 16 + rl) * 256 + w * 64 + (lane & 7) * 8] = v;
        }
    }
}

// ---------------------------------------------------------------------------
// Fused agg + GEMM: per 16-row panel, gather-aggregate 16 nodes into an LDS
// A-tile (16 thr/node, f32 accum, bias+relu, f16 — same rounding chain as the
// old agg->Asw->gemm path), barrier, MFMA with register-resident B.
// MODE 0: f16 row-major out (next gather source). MODE 1: f32 + head bias.
// ---------------------------------------------------------------------------

template <int MODE>
__global__ __launch_bounds__(256) void aggemm_kernel(const _Float16* __restrict__ xt,
                                                     const int* __restrict__ row_ptr,
                                                     const int2* __restrict__ csr,
                                                     const float* __restrict__ bias_agg,
                                                     const _Float16* __restrict__ Bsw,
                                                     const float* __restrict__ bias_head,
                                                     void* __restrict__ Cout) {
    __shared__ __align__(16) _Float16 atile[16 * 264];      // row-major, pad 264
    __shared__ __align__(16) char ebraw[4][16 * 68 * 4];

    const int t = threadIdx.x;
    const int w = t >> 6, lane = t & 63;
    const int lr = lane & 15;
    const int ar = t >> 4;        // node row 0..15
    const int d0 = (t & 15) * 16; // this thread's 16 features

    f16x8 bf[4][8];
#pragma unroll
    for (int cp4 = 0; cp4 < 4; ++cp4)
#pragma unroll
        for (int kb = 0; kb < 8; ++kb)
            bf[cp4][kb] = *(const f16x8*)&Bsw[(size_t)((w * 4 + cp4) * 8 + kb) * 512 + lane * 8];

    float bc[4];
    if (MODE == 1) {
#pragma unroll
        for (int cp4 = 0; cp4 < 4; ++cp4) bc[cp4] = bias_head[w * 64 + cp4 * 16 + lr];
    }

    float bgs[16];
#pragma unroll
    for (int q = 0; q < 4; ++q) {
        float4 v = *(const float4*)&bias_agg[d0 + q * 4];
        bgs[q * 4 + 0] = v.x; bgs[q * 4 + 1] = v.y;
        bgs[q * 4 + 2] = v.z; bgs[q * 4 + 3] = v.w;
    }

    for (int p = blockIdx.x; p < N_PANELS; p += GB) {
        // ---- aggregation phase (no LDS) ----
        const int v = p * 16 + ar;
        const int s0 = row_ptr[v];
        const int s1 = row_ptr[v + 1];
        float acc[16];
#pragma unroll
        for (int j = 0; j < 16; ++j) acc[j] = 0.f;

        int i = s0;
        for (; i + 2 <= s1; i += 2) {
            int2 h0 = csr[i], h1 = csr[i + 1];
            f16x8 a0 = *(const f16x8*)&xt[(size_t)h0.x * 256 + d0];
            f16x8 a1 = *(const f16x8*)&xt[(size_t)h0.x * 256 + d0 + 8];
            f16x8 b0 = *(const f16x8*)&xt[(size_t)h1.x * 256 + d0];
            f16x8 b1 = *(const f16x8*)&xt[(size_t)h1.x * 256 + d0 + 8];
            float w0 = __int_as_float(h0.y);
            float w1 = __int_as_float(h1.y);
#pragma unroll
            for (int j = 0; j < 8; ++j) {
                acc[j]     += (float)a0[j] * w0;
                acc[8 + j] += (float)a1[j] * w0;
            }
#pragma unroll
            for (int j = 0; j < 8; ++j) {
                acc[j]     += (float)b0[j] * w1;
                acc[8 + j] += (float)b1[j] * w1;
            }
        }
        if (i < s1) {
            int2 h0 = csr[i];
            f16x8 a0 = *(const f16x8*)&xt[(size_t)h0.x * 256 + d0];
            f16x8 a1 = *(const f16x8*)&xt[(size_t)h0.x * 256 + d0 + 8];
            float w0 = __int_as_float(h0.y);
#pragma unroll
            for (int j = 0; j < 8; ++j) {
                acc[j]     += (float)a0[j] * w0;
                acc[8 + j] += (float)a1[j] * w0;
            }
        }

        f16x8 o0, o1;
#pragma unroll
        for (int j = 0; j < 8; ++j) {
            float r0 = acc[j] + bgs[j];
            float r1 = acc[8 + j] + bgs[8 + j];
            r0 = r0 > 0.f ? r0 : 0.f;
            r1 = r1 > 0.f ? r1 : 0.f;
            o0[j] = (_Float16)r0;
            o1[j] = (_Float16)r1;
        }

        __syncthreads();   // prior panel's MFMA reads of atile complete
        *(f16x8*)&atile[ar * 264 + d0] = o0;
        *(f16x8*)&atile[ar * 264 + d0 + 8] = o1;
        __syncthreads();   // A-tile visible to all waves

        // ---- MFMA phase ----
        f16x8 afr[8];
#pragma unroll
        for (int kb = 0; kb < 8; ++kb)
            afr[kb] = *(const f16x8*)&atile[lr * 264 + kb * 32 + (lane >> 4) * 8];

        f32x4 acc2[4];
#pragma unroll
        for (int cp4 = 0; cp4 < 4; ++cp4) acc2[cp4] = (f32x4){0.f, 0.f, 0.f, 0.f};
#pragma unroll
        for (int kb = 0; kb < 8; ++kb)
#pragma unroll
            for (int cp4 = 0; cp4 < 4; ++cp4)
                acc2[cp4] = mfma_f16(afr[kb], bf[cp4][kb], acc2[cp4]);

        // D: row = 4*(lane>>4)+reg, col = lane&15  [m89-verified]
        const int rq = 4 * (lane >> 4);
        if (MODE == 0) {
            _Float16* eb = (_Float16*)ebraw[w];
#pragma unroll
            for (int cp4 = 0; cp4 < 4; ++cp4)
#pragma unroll
                for (int rr = 0; rr < 4; ++rr)
                    eb[(rq + rr) * 72 + cp4 * 16 + lr] = (_Float16)acc2[cp4][rr];
            _Float16* xp = (_Float16*)Cout;
#pragma unroll
            for (int it = 0; it < 2; ++it) {
                int rl = it * 8 + (lane >> 3);
                f16x8 vv = *(const f16x8*)&eb[rl * 72 + (lane & 7) * 8];
                *(f16x8*)&xp[(size_t)(p * 16 + rl) * 256 + w * 64 + (lane & 7) * 8] = vv;
            }
        } else {
            float* eb = (float*)ebraw[w];
#pragma unroll
            for (int cp4 = 0; cp4 < 4; ++cp4)
#pragma unroll
                for (int rr = 0; rr < 4; ++rr)
                    eb[(rq + rr) * 68 + cp4 * 16 + lr] = acc2[cp4][rr] + bc[cp4];
            float* op = (float*)Cout;
#pragma unroll
            for (int it = 0; it < 4; ++it) {
                int rl = it * 4 + (lane >> 4);
                float4 vv = *(const float4*)&eb[rl * 68 + lr * 4];
                *(float4*)&op[(size_t)(p * 16 + rl) * 256 + w * 64 + lr * 4] = vv;
            }
        }
    }
}

// ---------------------------------------------------------------------------

extern "C" void kernel_launch(void* const* d_in, const int* in_sizes, int n_in,
                              void* d_out, int out_size, void* d_ws, size_t ws_size,
                              hipStream_t stream) {
    (void)in_sizes; (void)n_in; (void)out_size; (void)ws_size;
    const float* h5 = (const float*)d_in[0];
    const int*   ei = (const int*)d_in[1];
    const float* ew = (const float*)d_in[2];
    const float* W6 = (const float*)d_in[3];
    const float* b6 = (const float*)d_in[4];
    const float* W7 = (const float*)d_in[5];
    const float* b7 = (const float*)d_in[6];
    const float* Wp = (const float*)d_in[7];
    const float* bp = (const float*)d_in[8];
    float* out = (float*)d_out;

    char* ws = (char*)d_ws;
    size_t off = 0;
    auto alloc = [&](size_t bytes) -> void* {
        void* p = ws + off;
        off = (off + bytes + 255) & ~(size_t)255;
        return p;
    };

    // single zeroed region: pk_out | pk_in | cur (all u32)
    char* zblk = (char*)alloc(ZBYTES);
    unsigned* pk_out = (unsigned*)zblk;
    unsigned* pk_in  = (unsigned*)(zblk + N_NODES * 4);
    int* cur = (int*)(zblk + N_NODES * 8);

    float* deg_out = (float*)alloc(N_NODES * 4);
    float* deg_in  = (float*)alloc(N_NODES * 4);
    int*   row_ptr = (int*)alloc((N_NODES + 1) * 4);
    int*   partial = (int*)alloc(SCAN_NB * 4);
    int2*  csr     = (int2*)alloc(N_EDGES * 8);
    _Float16* Bsw  = (_Float16*)alloc(3 * 65536 * 2);
    _Float16* Asw  = (_Float16*)alloc((size_t)N_NODES * 256 * 2);  // swz A, then F1 out
    _Float16* xt   = (_Float16*)alloc((size_t)N_NODES * 256 * 2);

    const int Z16 = ZBYTES / 16;

    zero_kernel<<<(Z16 + 255) / 256, 256, 0, stream>>>((int4*)zblk, Z16);

    // deg (compact u32) ∥ wsplit ∥ asplit
    p1_kernel<<<DEGB + WB + AB, 256, 0, stream>>>(ei, ew, pk_out, pk_in,
                                                  W6, W7, Wp, Bsw, h5, Asw);

    scan1_kernel<<<SCAN_NB, 256, 0, stream>>>(pk_in, pk_out, deg_in, deg_out, partial);
    scan23_kernel<<<SCAN_NB, 256, 0, stream>>>(pk_in, partial, row_ptr);

    // fill (compact) ∥ gemm layer-1 (swizzled f16 A -> row-major xt)
    p2_kernel<<<FILLB + GB, 256, 0, stream>>>(ei, ew, deg_out, deg_in, row_ptr, cur, csr,
                                              Asw, Bsw, xt);

    // fused agg(b6) + W7 GEMM: xt -> Asw buffer (row-major f16; Asw free after gemm1)
    aggemm_kernel<0><<<GB, 256, 0, stream>>>(xt, row_ptr, csr, b6, Bsw + 65536,
                                             nullptr, Asw);

    // fused agg(b7) + Wp GEMM + bp: Asw buffer -> f32 out
    aggemm_kernel<1><<<GB, 256, 0, stream>>>(Asw, row_ptr, csr, b7, Bsw + 2 * 65536,
                                             bp, out);
}

// Round 14
// 161.052 us; speedup vs baseline: 1.0342x; 1.0342x over previous
//
#include <hip/hip_runtime.h>

#define N_NODES 50000
#define N_PANELS 3125            // 50000 / 16 exactly
#define N_EDGES 300000
#define EPS_F 1e-12f
#define DEGB 64                           // compact deg blocks (grid-stride)
#define WB 96                             // wsplit blocks
#define AB (N_NODES * 32 / 256)           // 6250 asplit blocks
#define FILLB 128                         // compact fill blocks (grid-stride)
#define GB 512                            // gemm grid (grid-stride over panels)
#define SCAN_NB ((N_NODES + 255) / 256)   // 196
#define ZBYTES (N_NODES * 12)             // pk_out(4) + pk_in(4) + cur(4)

typedef _Float16 f16x8 __attribute__((ext_vector_type(8)));
typedef float f32x4 __attribute__((ext_vector_type(4)));

static __device__ inline f32x4 mfma_f16(f16x8 a, f16x8 b, f32x4 c) {
    return __builtin_amdgcn_mfma_f32_16x16x32_f16(a, b, c, 0, 0, 0);
}

// fragment-ready swizzled layout for a [R][256] f16 matrix:
// element (row, k) at ((row>>4)*8 + (k>>5))*512 + ((k>>3)&3)*128 + (row&15)*8 + (k&7)
static __device__ inline size_t swz(int row, int l) {
    return ((size_t)(row >> 4) * 8 + (l >> 2)) * 512 + (size_t)((l & 3) * 128 + (row & 15) * 8);
}

// ---------------------------------------------------------------------------
// Workspace zero-init
// ---------------------------------------------------------------------------

__global__ __launch_bounds__(256) void zero_kernel(int4* __restrict__ p, int n16) {
    int i = blockIdx.x * 256 + threadIdx.x;
    if (i < n16) p[i] = make_int4(0, 0, 0, 0);
}

// ---------------------------------------------------------------------------
// P1: deg (u32 packed fixed-point atomics, compact) ∥ wsplit ∥ asplit
//   pk_in[d]  += (1<<24) | (w * 2^18)   (cnt in bits 24..31, sum in 0..23)
//   pk_out[s] += (w * 2^18)
// deg<=~35, sum(w)<64 -> no overflow/carry. Quantization 2^-18 (negligible).
// ---------------------------------------------------------------------------

__global__ __launch_bounds__(256) void p1_kernel(const int* __restrict__ ei,
                                                 const float* __restrict__ ew,
                                                 unsigned* __restrict__ pk_out,
                                                 unsigned* __restrict__ pk_in,
                                                 const float* __restrict__ W6,
                                                 const float* __restrict__ W7,
                                                 const float* __restrict__ Wp,
                                                 _Float16* __restrict__ Bsw,
                                                 const float* __restrict__ h5,
                                                 _Float16* __restrict__ Asw) {
    int b = blockIdx.x;
    if (b < DEGB) {
        for (int e = b * 256 + (int)threadIdx.x; e < N_EDGES; e += DEGB * 256) {
            int s = ei[e];
            int d = ei[N_EDGES + e];
            unsigned wfx = (unsigned)(ew[e] * 262144.0f);   // 2^18
            atomicAdd(&pk_out[s], wfx);
            atomicAdd(&pk_in[d], (1u << 24) | wfx);
        }
    } else if (b < DEGB + WB) {
        int bb = b - DEGB;                // 0..95
        int wsel = bb >> 5;               // 0..2
        const float* W = (wsel == 0) ? W6 : (wsel == 1) ? W7 : Wp;
        int id = (bb & 31) * 256 + threadIdx.x;   // 0..8191
        int n = id >> 5, l = id & 31;
        f16x8 o;
#pragma unroll
        for (int j = 0; j < 8; ++j)
            o[j] = (_Float16)W[(l * 8 + j) * 256 + n];
        *(f16x8*)&Bsw[(size_t)wsel * 65536 + swz(n, l)] = o;
    } else {
        int tid = (b - DEGB - WB) * 256 + threadIdx.x;   // 0 .. 1,600,000 exact
        int row = tid >> 5, l = tid & 31;
        const float* p = &h5[(size_t)row * 256 + l * 8];
        float4 v0 = *(const float4*)p;
        float4 v1 = *(const float4*)(p + 4);
        f16x8 o;
        o[0] = (_Float16)v0.x; o[1] = (_Float16)v0.y;
        o[2] = (_Float16)v0.z; o[3] = (_Float16)v0.w;
        o[4] = (_Float16)v1.x; o[5] = (_Float16)v1.y;
        o[6] = (_Float16)v1.z; o[7] = (_Float16)v1.w;
        *(f16x8*)&Asw[swz(row, l)] = o;
    }
}

// --- scan: per-block reduce, then fused (partial-scan + local scan) ---------

__global__ __launch_bounds__(256) void scan1_kernel(const unsigned* __restrict__ pk_in,
                                                    const unsigned* __restrict__ pk_out,
                                                    float* __restrict__ deg_in,
                                                    float* __restrict__ deg_out,
                                                    int* __restrict__ partial) {
    __shared__ int sh[256];
    int i = blockIdx.x * 256 + threadIdx.x;
    int c = 0;
    if (i < N_NODES) {
        unsigned p = pk_in[i];
        c = (int)(p >> 24);
        deg_in[i] = (float)(p & 0xFFFFFFu) * 0x1p-18f;
        deg_out[i] = (float)pk_out[i] * 0x1p-18f;
    }
    sh[threadIdx.x] = c;
    __syncthreads();
    for (int off = 128; off > 0; off >>= 1) {
        if (threadIdx.x < (unsigned)off) sh[threadIdx.x] += sh[threadIdx.x + off];
        __syncthreads();
    }
    if (threadIdx.x == 0) partial[blockIdx.x] = sh[0];
}

// fused scan2+scan3: every block redundantly scans the 196 partials (trivial)
__global__ __launch_bounds__(256) void scan23_kernel(const unsigned* __restrict__ pk_in,
                                                     const int* __restrict__ partial,
                                                     int* __restrict__ row_ptr) {
    __shared__ int ps[256];
    __shared__ int sh[256];
    int t = threadIdx.x;
    int pv = (t < SCAN_NB) ? partial[t] : 0;
    ps[t] = pv;
    __syncthreads();
    for (int off = 1; off < 256; off <<= 1) {
        int x = (t >= off) ? ps[t - off] : 0;
        __syncthreads();
        ps[t] += x;
        __syncthreads();
    }
    int incl = ps[t];
    __syncthreads();
    ps[t] = incl - pv;    // exclusive prefix of partials
    __syncthreads();
    const int boff = ps[blockIdx.x];

    int i = blockIdx.x * 256 + t;
    int v = (i < N_NODES) ? (int)(pk_in[i] >> 24) : 0;
    sh[t] = v;
    __syncthreads();
    for (int off = 1; off < 256; off <<= 1) {
        int x = (t >= off) ? sh[t - off] : 0;
        __syncthreads();
        sh[t] += x;
        __syncthreads();
    }
    if (i < N_NODES) row_ptr[i] = sh[t] - v + boff;
    if (i == 0) row_ptr[N_NODES] = N_EDGES;
}

// ---------------------------------------------------------------------------
// P2: fill (128 compact grid-strided blocks) ∥ gemm layer-1 (swizzled A).
// ---------------------------------------------------------------------------

__global__ __launch_bounds__(256) void p2_kernel(const int* __restrict__ ei,
                                                 const float* __restrict__ ew,
                                                 const float* __restrict__ deg_out,
                                                 const float* __restrict__ deg_in,
                                                 const int* __restrict__ row_ptr,
                                                 int* __restrict__ cur,
                                                 int2* __restrict__ csr,
                                                 const _Float16* __restrict__ Asw,
                                                 const _Float16* __restrict__ Bsw,
                                                 _Float16* __restrict__ xt) {
    __shared__ __align__(16) _Float16 ebuf[4][16 * 72];

    if (blockIdx.x < FILLB) {
        for (int e = blockIdx.x * 256 + (int)threadIdx.x; e < N_EDGES; e += FILLB * 256) {
            int s = ei[e];
            int d = ei[N_EDGES + e];
            float nm = ew[e] * rsqrtf(deg_out[s] * deg_in[d] + EPS_F);
            int pos = atomicAdd(&cur[d], 1);
            csr[row_ptr[d] + pos] = make_int2(s, __float_as_int(nm));
        }
        return;
    }

    const int t = threadIdx.x;
    const int w = t >> 6, lane = t & 63;

    f16x8 bf[4][8];
#pragma unroll
    for (int cp4 = 0; cp4 < 4; ++cp4)
#pragma unroll
        for (int kb = 0; kb < 8; ++kb)
            bf[cp4][kb] = *(const f16x8*)&Bsw[(size_t)((w * 4 + cp4) * 8 + kb) * 512 + lane * 8];

    for (int p = blockIdx.x - FILLB; p < N_PANELS; p += GB) {
        const _Float16* abase = &Asw[(size_t)p * 4096 + lane * 8];
        f16x8 af[8];
#pragma unroll
        for (int kb = 0; kb < 8; ++kb)
            af[kb] = *(const f16x8*)&abase[kb * 512];

        f32x4 acc[4];
#pragma unroll
        for (int cp4 = 0; cp4 < 4; ++cp4) acc[cp4] = (f32x4){0.f, 0.f, 0.f, 0.f};
#pragma unroll
        for (int kb = 0; kb < 8; ++kb)
#pragma unroll
            for (int cp4 = 0; cp4 < 4; ++cp4)
                acc[cp4] = mfma_f16(af[kb], bf[cp4][kb], acc[cp4]);

        // D: row = 4*(lane>>4)+reg, col = lane&15  [m89-verified]
        _Float16* eb = ebuf[w];
        const int rq = 4 * (lane >> 4);
        const int lr = lane & 15;
#pragma unroll
        for (int cp4 = 0; cp4 < 4; ++cp4)
#pragma unroll
            for (int rr = 0; rr < 4; ++rr)
                eb[(rq + rr) * 72 + cp4 * 16 + lr] = (_Float16)acc[cp4][rr];
#pragma unroll
        for (int it = 0; it < 2; ++it) {
            int rl = it * 8 + (lane >> 3);
            f16x8 v = *(const f16x8*)&eb[rl * 72 + (lane & 7) * 8];
            *(f16x8*)&xt[(size_t)(p * 16 + rl) * 256 + w * 64 + (lane & 7) * 8] = v;
        }
    }
}

// ---------------------------------------------------------------------------
// gemm (swizzled f16 A): MODE 0 -> f16 row-major xt; MODE 1 -> f32 + bias out
// (MODE 1 epilogue bounces f32 through LDS for 256B-per-row coalesced stores)
// ---------------------------------------------------------------------------

template <int MODE>
__global__ __launch_bounds__(256) void gemm_f16(const _Float16* __restrict__ Asw,
                                                const _Float16* __restrict__ Bsw,
                                                const float* __restrict__ bias,
                                                void* __restrict__ Cout) {
    __shared__ __align__(16) char ebraw[4][16 * 68 * 4];   // fits f16x72 & f32x68

    const int t = threadIdx.x;
    const int w = t >> 6, lane = t & 63;
    const int lr = lane & 15;

    f16x8 bf[4][8];
#pragma unroll
    for (int cp4 = 0; cp4 < 4; ++cp4)
#pragma unroll
        for (int kb = 0; kb < 8; ++kb)
            bf[cp4][kb] = *(const f16x8*)&Bsw[(size_t)((w * 4 + cp4) * 8 + kb) * 512 + lane * 8];

    float bc[4];
    if (MODE == 1) {
#pragma unroll
        for (int cp4 = 0; cp4 < 4; ++cp4) bc[cp4] = bias[w * 64 + cp4 * 16 + lr];
    }

    for (int p = blockIdx.x; p < N_PANELS; p += GB) {
        const _Float16* abase = &Asw[(size_t)p * 4096 + lane * 8];
        f16x8 af[8];
#pragma unroll
        for (int kb = 0; kb < 8; ++kb)
            af[kb] = *(const f16x8*)&abase[kb * 512];

        f32x4 acc[4];
#pragma unroll
        for (int cp4 = 0; cp4 < 4; ++cp4) acc[cp4] = (f32x4){0.f, 0.f, 0.f, 0.f};
#pragma unroll
        for (int kb = 0; kb < 8; ++kb)
#pragma unroll
            for (int cp4 = 0; cp4 < 4; ++cp4)
                acc[cp4] = mfma_f16(af[kb], bf[cp4][kb], acc[cp4]);

        const int rq = 4 * (lane >> 4);
        if (MODE == 0) {
            _Float16* eb = (_Float16*)ebraw[w];
#pragma unroll
            for (int cp4 = 0; cp4 < 4; ++cp4)
#pragma unroll
                for (int rr = 0; rr < 4; ++rr)
                    eb[(rq + rr) * 72 + cp4 * 16 + lr] = (_Float16)acc[cp4][rr];
            _Float16* xp = (_Float16*)Cout;
#pragma unroll
            for (int it = 0; it < 2; ++it) {
                int rl = it * 8 + (lane >> 3);
                f16x8 v = *(const f16x8*)&eb[rl * 72 + (lane & 7) * 8];
                *(f16x8*)&xp[(size_t)(p * 16 + rl) * 256 + w * 64 + (lane & 7) * 8] = v;
            }
        } else {
            float* eb = (float*)ebraw[w];
#pragma unroll
            for (int cp4 = 0; cp4 < 4; ++cp4)
#pragma unroll
                for (int rr = 0; rr < 4; ++rr)
                    eb[(rq + rr) * 68 + cp4 * 16 + lr] = acc[cp4][rr] + bc[cp4];
            float* op = (float*)Cout;
#pragma unroll
            for (int it = 0; it < 4; ++it) {
                int rl = it * 4 + (lane >> 4);
                float4 v = *(const float4*)&eb[rl * 68 + lr * 4];
                *(float4*)&op[(size_t)(p * 16 + rl) * 256 + w * 64 + lr * 4] = v;
            }
        }
    }
}

// ---------------------------------------------------------------------------
// Aggregation: 8 nodes/block, 32 lanes/node, 8 features/lane, 4 gathers in
// flight; packed {src,norm} headers; writes fragment-swizzled f16 output.
// ---------------------------------------------------------------------------

__global__ __launch_bounds__(256) void agg_kernel(const _Float16* __restrict__ xt,
                                                  const int* __restrict__ row_ptr,
                                                  const int2* __restrict__ csr,
                                                  const float* __restrict__ bias,
                                                  _Float16* __restrict__ Asw) {
    const int g = threadIdx.x >> 5;
    const int l = threadIdx.x & 31;
    const int v = blockIdx.x * 8 + g;
    const int d0 = l * 8;

    const int s0 = row_ptr[v];
    const int s1 = row_ptr[v + 1];

    float acc[8] = {0.f, 0.f, 0.f, 0.f, 0.f, 0.f, 0.f, 0.f};

    int i = s0;
    for (; i + 4 <= s1; i += 4) {
        int2 hd[4];
#pragma unroll
        for (int u = 0; u < 4; ++u) hd[u] = csr[i + u];
        f16x8 val[4];
#pragma unroll
        for (int u = 0; u < 4; ++u)
            val[u] = *(const f16x8*)&xt[(size_t)hd[u].x * 256 + d0];
#pragma unroll
        for (int u = 0; u < 4; ++u) {
            float wv = __int_as_float(hd[u].y);
#pragma unroll
            for (int j = 0; j < 8; ++j)
                acc[j] += (float)val[u][j] * wv;
        }
    }
    {
        int rem = s1 - i;
        int2 hd[3];
#pragma unroll
        for (int u = 0; u < 3; ++u)
            hd[u] = (u < rem) ? csr[i + u] : make_int2(0, 0);
        f16x8 val[3];
#pragma unroll
        for (int u = 0; u < 3; ++u)
            val[u] = *(const f16x8*)&xt[(size_t)hd[u].x * 256 + d0];
#pragma unroll
        for (int u = 0; u < 3; ++u) {
            float wv = __int_as_float(hd[u].y);
#pragma unroll
            for (int j = 0; j < 8; ++j)
                acc[j] += (float)val[u][j] * wv;
        }
    }

    f16x8 o;
#pragma unroll
    for (int j = 0; j < 8; ++j) {
        float r = acc[j] + bias[d0 + j];
        r = r > 0.f ? r : 0.f;
        o[j] = (_Float16)r;
    }
    *(f16x8*)&Asw[swz(v, l)] = o;
}

// ---------------------------------------------------------------------------

extern "C" void kernel_launch(void* const* d_in, const int* in_sizes, int n_in,
                              void* d_out, int out_size, void* d_ws, size_t ws_size,
                              hipStream_t stream) {
    (void)in_sizes; (void)n_in; (void)out_size; (void)ws_size;
    const float* h5 = (const float*)d_in[0];
    const int*   ei = (const int*)d_in[1];
    const float* ew = (const float*)d_in[2];
    const float* W6 = (const float*)d_in[3];
    const float* b6 = (const float*)d_in[4];
    const float* W7 = (const float*)d_in[5];
    const float* b7 = (const float*)d_in[6];
    const float* Wp = (const float*)d_in[7];
    const float* bp = (const float*)d_in[8];
    float* out = (float*)d_out;

    char* ws = (char*)d_ws;
    size_t off = 0;
    auto alloc = [&](size_t bytes) -> void* {
        void* p = ws + off;
        off = (off + bytes + 255) & ~(size_t)255;
        return p;
    };

    // single zeroed region: pk_out | pk_in | cur (all u32)
    char* zblk = (char*)alloc(ZBYTES);
    unsigned* pk_out = (unsigned*)zblk;
    unsigned* pk_in  = (unsigned*)(zblk + N_NODES * 4);
    int* cur = (int*)(zblk + N_NODES * 8);

    float* deg_out = (float*)alloc(N_NODES * 4);
    float* deg_in  = (float*)alloc(N_NODES * 4);
    int*   row_ptr = (int*)alloc((N_NODES + 1) * 4);
    int*   partial = (int*)alloc(SCAN_NB * 4);
    int2*  csr     = (int2*)alloc(N_EDGES * 8);
    _Float16* Bsw  = (_Float16*)alloc(3 * 65536 * 2);
    _Float16* Asw  = (_Float16*)alloc((size_t)N_NODES * 256 * 2);
    _Float16* xt   = (_Float16*)alloc((size_t)N_NODES * 256 * 2);

    const int Z16 = ZBYTES / 16;

    zero_kernel<<<(Z16 + 255) / 256, 256, 0, stream>>>((int4*)zblk, Z16);

    // deg (compact u32) ∥ wsplit ∥ asplit
    p1_kernel<<<DEGB + WB + AB, 256, 0, stream>>>(ei, ew, pk_out, pk_in,
                                                  W6, W7, Wp, Bsw, h5, Asw);

    scan1_kernel<<<SCAN_NB, 256, 0, stream>>>(pk_in, pk_out, deg_in, deg_out, partial);
    scan23_kernel<<<SCAN_NB, 256, 0, stream>>>(pk_in, partial, row_ptr);

    // fill (compact) ∥ gemm layer-1 (swizzled f16 A)
    p2_kernel<<<FILLB + GB, 256, 0, stream>>>(ei, ew, deg_out, deg_in, row_ptr, cur, csr,
                                              Asw, Bsw, xt);

    agg_kernel<<<N_NODES / 8, 256, 0, stream>>>(xt, row_ptr, csr, b6, Asw);
    gemm_f16<0><<<GB, 256, 0, stream>>>(Asw, Bsw + 65536, nullptr, xt);
    agg_kernel<<<N_NODES / 8, 256, 0, stream>>>(xt, row_ptr, csr, b7, Asw);
    gemm_f16<1><<<GB, 256, 0, stream>>>(Asw, Bsw + 2 * 65536, bp, out);
}

// Round 15
// 160.489 us; speedup vs baseline: 1.0378x; 1.0035x over previous
//
#include <hip/hip_runtime.h>

#define N_NODES 50000
#define N_PANELS 3125            // 50000 / 16 exactly
#define N_EDGES 300000
#define EPS_F 1e-12f
#define DEGB 64                           // compact deg blocks (grid-stride)
#define WB 96                             // wsplit blocks
#define AB (N_NODES * 32 / 256)           // 6250 asplit blocks
#define FILLB 128                         // compact fill blocks (grid-stride)
#define GB 512                            // gemm grid (grid-stride over panels)
#define SCAN_NB ((N_NODES + 255) / 256)   // 196
#define ZBYTES (N_NODES * 8)              // pk_out(4) + pk_in(4)

typedef _Float16 f16x8 __attribute__((ext_vector_type(8)));
typedef float f32x4 __attribute__((ext_vector_type(4)));

static __device__ inline f32x4 mfma_f16(f16x8 a, f16x8 b, f32x4 c) {
    return __builtin_amdgcn_mfma_f32_16x16x32_f16(a, b, c, 0, 0, 0);
}

// fragment-ready swizzled layout for a [R][256] f16 matrix:
// element (row, k) at ((row>>4)*8 + (k>>5))*512 + ((k>>3)&3)*128 + (row&15)*8 + (k&7)
static __device__ inline size_t swz(int row, int l) {
    return ((size_t)(row >> 4) * 8 + (l >> 2)) * 512 + (size_t)((l & 3) * 128 + (row & 15) * 8);
}

// ---------------------------------------------------------------------------
// Workspace zero-init
// ---------------------------------------------------------------------------

__global__ __launch_bounds__(256) void zero_kernel(int4* __restrict__ p, int n16) {
    int i = blockIdx.x * 256 + threadIdx.x;
    if (i < n16) p[i] = make_int4(0, 0, 0, 0);
}

// ---------------------------------------------------------------------------
// P1: deg (u32 packed atomics; pk_in atomic RETURNS rank) ∥ wsplit ∥ asplit
//   pk_in[d]  += (1<<24) | (w * 2^18)   -> old>>24 is this edge's CSR rank
//   pk_out[s] += (w * 2^18)             (fire-and-forget)
// deg<=~35, sum(w)<64 -> no overflow/carry. Quantization 2^-18 (negligible).
// ---------------------------------------------------------------------------

__global__ __launch_bounds__(256) void p1_kernel(const int* __restrict__ ei,
                                                 const float* __restrict__ ew,
                                                 unsigned* __restrict__ pk_out,
                                                 unsigned* __restrict__ pk_in,
                                                 unsigned* __restrict__ rank,
                                                 const float* __restrict__ W6,
                                                 const float* __restrict__ W7,
                                                 const float* __restrict__ Wp,
                                                 _Float16* __restrict__ Bsw,
                                                 const float* __restrict__ h5,
                                                 _Float16* __restrict__ Asw) {
    int b = blockIdx.x;
    if (b < DEGB) {
        for (int e = b * 256 + (int)threadIdx.x; e < N_EDGES; e += DEGB * 256) {
            int s = ei[e];
            int d = ei[N_EDGES + e];
            unsigned wfx = (unsigned)(ew[e] * 262144.0f);   // 2^18
            atomicAdd(&pk_out[s], wfx);
            unsigned old = atomicAdd(&pk_in[d], (1u << 24) | wfx);
            rank[e] = old >> 24;
        }
    } else if (b < DEGB + WB) {
        int bb = b - DEGB;                // 0..95
        int wsel = bb >> 5;               // 0..2
        const float* W = (wsel == 0) ? W6 : (wsel == 1) ? W7 : Wp;
        int id = (bb & 31) * 256 + threadIdx.x;   // 0..8191
        int n = id >> 5, l = id & 31;
        f16x8 o;
#pragma unroll
        for (int j = 0; j < 8; ++j)
            o[j] = (_Float16)W[(l * 8 + j) * 256 + n];
        *(f16x8*)&Bsw[(size_t)wsel * 65536 + swz(n, l)] = o;
    } else {
        int tid = (b - DEGB - WB) * 256 + threadIdx.x;   // 0 .. 1,600,000 exact
        int row = tid >> 5, l = tid & 31;
        const float* p = &h5[(size_t)row * 256 + l * 8];
        float4 v0 = *(const float4*)p;
        float4 v1 = *(const float4*)(p + 4);
        f16x8 o;
        o[0] = (_Float16)v0.x; o[1] = (_Float16)v0.y;
        o[2] = (_Float16)v0.z; o[3] = (_Float16)v0.w;
        o[4] = (_Float16)v1.x; o[5] = (_Float16)v1.y;
        o[6] = (_Float16)v1.z; o[7] = (_Float16)v1.w;
        *(f16x8*)&Asw[swz(row, l)] = o;
    }
}

// --- scan: per-block reduce, then fused (partial-scan + local scan) ---------

__global__ __launch_bounds__(256) void scan1_kernel(const unsigned* __restrict__ pk_in,
                                                    const unsigned* __restrict__ pk_out,
                                                    float* __restrict__ deg_in,
                                                    float* __restrict__ deg_out,
                                                    int* __restrict__ partial) {
    __shared__ int sh[256];
    int i = blockIdx.x * 256 + threadIdx.x;
    int c = 0;
    if (i < N_NODES) {
        unsigned p = pk_in[i];
        c = (int)(p >> 24);
        deg_in[i] = (float)(p & 0xFFFFFFu) * 0x1p-18f;
        deg_out[i] = (float)pk_out[i] * 0x1p-18f;
    }
    sh[threadIdx.x] = c;
    __syncthreads();
    for (int off = 128; off > 0; off >>= 1) {
        if (threadIdx.x < (unsigned)off) sh[threadIdx.x] += sh[threadIdx.x + off];
        __syncthreads();
    }
    if (threadIdx.x == 0) partial[blockIdx.x] = sh[0];
}

// fused scan2+scan3: every block redundantly scans the 196 partials (trivial)
__global__ __launch_bounds__(256) void scan23_kernel(const unsigned* __restrict__ pk_in,
                                                     const int* __restrict__ partial,
                                                     int* __restrict__ row_ptr) {
    __shared__ int ps[256];
    __shared__ int sh[256];
    int t = threadIdx.x;
    int pv = (t < SCAN_NB) ? partial[t] : 0;
    ps[t] = pv;
    __syncthreads();
    for (int off = 1; off < 256; off <<= 1) {
        int x = (t >= off) ? ps[t - off] : 0;
        __syncthreads();
        ps[t] += x;
        __syncthreads();
    }
    int incl = ps[t];
    __syncthreads();
    ps[t] = incl - pv;    // exclusive prefix of partials
    __syncthreads();
    const int boff = ps[blockIdx.x];

    int i = blockIdx.x * 256 + t;
    int v = (i < N_NODES) ? (int)(pk_in[i] >> 24) : 0;
    sh[t] = v;
    __syncthreads();
    for (int off = 1; off < 256; off <<= 1) {
        int x = (t >= off) ? sh[t - off] : 0;
        __syncthreads();
        sh[t] += x;
        __syncthreads();
    }
    if (i < N_NODES) row_ptr[i] = sh[t] - v + boff;
    if (i == 0) row_ptr[N_NODES] = N_EDGES;
}

// ---------------------------------------------------------------------------
// P2: fill (ATOMIC-FREE: slot = row_ptr[d] + rank[e]) ∥ gemm layer-1.
// ---------------------------------------------------------------------------

__global__ __launch_bounds__(256) void p2_kernel(const int* __restrict__ ei,
                                                 const float* __restrict__ ew,
                                                 const unsigned* __restrict__ rank,
                                                 const float* __restrict__ deg_out,
                                                 const float* __restrict__ deg_in,
                                                 const int* __restrict__ row_ptr,
                                                 int2* __restrict__ csr,
                                                 const _Float16* __restrict__ Asw,
                                                 const _Float16* __restrict__ Bsw,
                                                 _Float16* __restrict__ xt) {
    __shared__ __align__(16) _Float16 ebuf[4][16 * 72];

    if (blockIdx.x < FILLB) {
        for (int e = blockIdx.x * 256 + (int)threadIdx.x; e < N_EDGES; e += FILLB * 256) {
            int s = ei[e];
            int d = ei[N_EDGES + e];
            float nm = ew[e] * rsqrtf(deg_out[s] * deg_in[d] + EPS_F);
            csr[row_ptr[d] + (int)rank[e]] = make_int2(s, __float_as_int(nm));
        }
        return;
    }

    const int t = threadIdx.x;
    const int w = t >> 6, lane = t & 63;

    f16x8 bf[4][8];
#pragma unroll
    for (int cp4 = 0; cp4 < 4; ++cp4)
#pragma unroll
        for (int kb = 0; kb < 8; ++kb)
            bf[cp4][kb] = *(const f16x8*)&Bsw[(size_t)((w * 4 + cp4) * 8 + kb) * 512 + lane * 8];

    for (int p = blockIdx.x - FILLB; p < N_PANELS; p += GB) {
        const _Float16* abase = &Asw[(size_t)p * 4096 + lane * 8];
        f16x8 af[8];
#pragma unroll
        for (int kb = 0; kb < 8; ++kb)
            af[kb] = *(const f16x8*)&abase[kb * 512];

        f32x4 acc[4];
#pragma unroll
        for (int cp4 = 0; cp4 < 4; ++cp4) acc[cp4] = (f32x4){0.f, 0.f, 0.f, 0.f};
#pragma unroll
        for (int kb = 0; kb < 8; ++kb)
#pragma unroll
            for (int cp4 = 0; cp4 < 4; ++cp4)
                acc[cp4] = mfma_f16(af[kb], bf[cp4][kb], acc[cp4]);

        // D: row = 4*(lane>>4)+reg, col = lane&15  [m89-verified]
        _Float16* eb = ebuf[w];
        const int rq = 4 * (lane >> 4);
        const int lr = lane & 15;
#pragma unroll
        for (int cp4 = 0; cp4 < 4; ++cp4)
#pragma unroll
            for (int rr = 0; rr < 4; ++rr)
                eb[(rq + rr) * 72 + cp4 * 16 + lr] = (_Float16)acc[cp4][rr];
#pragma unroll
        for (int it = 0; it < 2; ++it) {
            int rl = it * 8 + (lane >> 3);
            f16x8 v = *(const f16x8*)&eb[rl * 72 + (lane & 7) * 8];
            *(f16x8*)&xt[(size_t)(p * 16 + rl) * 256 + w * 64 + (lane & 7) * 8] = v;
        }
    }
}

// ---------------------------------------------------------------------------
// gemm (swizzled f16 A): MODE 0 -> f16 row-major xt; MODE 1 -> f32 + bias out
// (MODE 1 epilogue bounces f32 through LDS for 256B-per-row coalesced stores)
// ---------------------------------------------------------------------------

template <int MODE>
__global__ __launch_bounds__(256) void gemm_f16(const _Float16* __restrict__ Asw,
                                                const _Float16* __restrict__ Bsw,
                                                const float* __restrict__ bias,
                                                void* __restrict__ Cout) {
    __shared__ __align__(16) char ebraw[4][16 * 68 * 4];   // fits f16x72 & f32x68

    const int t = threadIdx.x;
    const int w = t >> 6, lane = t & 63;
    const int lr = lane & 15;

    f16x8 bf[4][8];
#pragma unroll
    for (int cp4 = 0; cp4 < 4; ++cp4)
#pragma unroll
        for (int kb = 0; kb < 8; ++kb)
            bf[cp4][kb] = *(const f16x8*)&Bsw[(size_t)((w * 4 + cp4) * 8 + kb) * 512 + lane * 8];

    float bc[4];
    if (MODE == 1) {
#pragma unroll
        for (int cp4 = 0; cp4 < 4; ++cp4) bc[cp4] = bias[w * 64 + cp4 * 16 + lr];
    }

    for (int p = blockIdx.x; p < N_PANELS; p += GB) {
        const _Float16* abase = &Asw[(size_t)p * 4096 + lane * 8];
        f16x8 af[8];
#pragma unroll
        for (int kb = 0; kb < 8; ++kb)
            af[kb] = *(const f16x8*)&abase[kb * 512];

        f32x4 acc[4];
#pragma unroll
        for (int cp4 = 0; cp4 < 4; ++cp4) acc[cp4] = (f32x4){0.f, 0.f, 0.f, 0.f};
#pragma unroll
        for (int kb = 0; kb < 8; ++kb)
#pragma unroll
            for (int cp4 = 0; cp4 < 4; ++cp4)
                acc[cp4] = mfma_f16(af[kb], bf[cp4][kb], acc[cp4]);

        const int rq = 4 * (lane >> 4);
        if (MODE == 0) {
            _Float16* eb = (_Float16*)ebraw[w];
#pragma unroll
            for (int cp4 = 0; cp4 < 4; ++cp4)
#pragma unroll
                for (int rr = 0; rr < 4; ++rr)
                    eb[(rq + rr) * 72 + cp4 * 16 + lr] = (_Float16)acc[cp4][rr];
            _Float16* xp = (_Float16*)Cout;
#pragma unroll
            for (int it = 0; it < 2; ++it) {
                int rl = it * 8 + (lane >> 3);
                f16x8 v = *(const f16x8*)&eb[rl * 72 + (lane & 7) * 8];
                *(f16x8*)&xp[(size_t)(p * 16 + rl) * 256 + w * 64 + (lane & 7) * 8] = v;
            }
        } else {
            float* eb = (float*)ebraw[w];
#pragma unroll
            for (int cp4 = 0; cp4 < 4; ++cp4)
#pragma unroll
                for (int rr = 0; rr < 4; ++rr)
                    eb[(rq + rr) * 68 + cp4 * 16 + lr] = acc[cp4][rr] + bc[cp4];
            float* op = (float*)Cout;
#pragma unroll
            for (int it = 0; it < 4; ++it) {
                int rl = it * 4 + (lane >> 4);
                float4 v = *(const float4*)&eb[rl * 68 + lr * 4];
                *(float4*)&op[(size_t)(p * 16 + rl) * 256 + w * 64 + lr * 4] = v;
            }
        }
    }
}

// ---------------------------------------------------------------------------
// Aggregation: 8 nodes/block, 32 lanes/node, 8 features/lane, 4 gathers in
// flight; packed {src,norm} headers; writes fragment-swizzled f16 output.
// ---------------------------------------------------------------------------

__global__ __launch_bounds__(256) void agg_kernel(const _Float16* __restrict__ xt,
                                                  const int* __restrict__ row_ptr,
                                                  const int2* __restrict__ csr,
                                                  const float* __restrict__ bias,
                                                  _Float16* __restrict__ Asw) {
    const int g = threadIdx.x >> 5;
    const int l = threadIdx.x & 31;
    const int v = blockIdx.x * 8 + g;
    const int d0 = l * 8;

    const int s0 = row_ptr[v];
    const int s1 = row_ptr[v + 1];

    float acc[8] = {0.f, 0.f, 0.f, 0.f, 0.f, 0.f, 0.f, 0.f};

    int i = s0;
    for (; i + 4 <= s1; i += 4) {
        int2 hd[4];
#pragma unroll
        for (int u = 0; u < 4; ++u) hd[u] = csr[i + u];
        f16x8 val[4];
#pragma unroll
        for (int u = 0; u < 4; ++u)
            val[u] = *(const f16x8*)&xt[(size_t)hd[u].x * 256 + d0];
#pragma unroll
        for (int u = 0; u < 4; ++u) {
            float wv = __int_as_float(hd[u].y);
#pragma unroll
            for (int j = 0; j < 8; ++j)
                acc[j] += (float)val[u][j] * wv;
        }
    }
    {
        int rem = s1 - i;
        int2 hd[3];
#pragma unroll
        for (int u = 0; u < 3; ++u)
            hd[u] = (u < rem) ? csr[i + u] : make_int2(0, 0);
        f16x8 val[3];
#pragma unroll
        for (int u = 0; u < 3; ++u)
            val[u] = *(const f16x8*)&xt[(size_t)hd[u].x * 256 + d0];
#pragma unroll
        for (int u = 0; u < 3; ++u) {
            float wv = __int_as_float(hd[u].y);
#pragma unroll
            for (int j = 0; j < 8; ++j)
                acc[j] += (float)val[u][j] * wv;
        }
    }

    f16x8 o;
#pragma unroll
    for (int j = 0; j < 8; ++j) {
        float r = acc[j] + bias[d0 + j];
        r = r > 0.f ? r : 0.f;
        o[j] = (_Float16)r;
    }
    *(f16x8*)&Asw[swz(v, l)] = o;
}

// ---------------------------------------------------------------------------

extern "C" void kernel_launch(void* const* d_in, const int* in_sizes, int n_in,
                              void* d_out, int out_size, void* d_ws, size_t ws_size,
                              hipStream_t stream) {
    (void)in_sizes; (void)n_in; (void)out_size; (void)ws_size;
    const float* h5 = (const float*)d_in[0];
    const int*   ei = (const int*)d_in[1];
    const float* ew = (const float*)d_in[2];
    const float* W6 = (const float*)d_in[3];
    const float* b6 = (const float*)d_in[4];
    const float* W7 = (const float*)d_in[5];
    const float* b7 = (const float*)d_in[6];
    const float* Wp = (const float*)d_in[7];
    const float* bp = (const float*)d_in[8];
    float* out = (float*)d_out;

    char* ws = (char*)d_ws;
    size_t off = 0;
    auto alloc = [&](size_t bytes) -> void* {
        void* p = ws + off;
        off = (off + bytes + 255) & ~(size_t)255;
        return p;
    };

    // single zeroed region: pk_out | pk_in (u32)
    char* zblk = (char*)alloc(ZBYTES);
    unsigned* pk_out = (unsigned*)zblk;
    unsigned* pk_in  = (unsigned*)(zblk + N_NODES * 4);

    unsigned* rank  = (unsigned*)alloc(N_EDGES * 4);
    float* deg_out = (float*)alloc(N_NODES * 4);
    float* deg_in  = (float*)alloc(N_NODES * 4);
    int*   row_ptr = (int*)alloc((N_NODES + 1) * 4);
    int*   partial = (int*)alloc(SCAN_NB * 4);
    int2*  csr     = (int2*)alloc(N_EDGES * 8);
    _Float16* Bsw  = (_Float16*)alloc(3 * 65536 * 2);
    _Float16* Asw  = (_Float16*)alloc((size_t)N_NODES * 256 * 2);
    _Float16* xt   = (_Float16*)alloc((size_t)N_NODES * 256 * 2);

    const int Z16 = ZBYTES / 16;

    zero_kernel<<<(Z16 + 255) / 256, 256, 0, stream>>>((int4*)zblk, Z16);

    // deg (compact u32, rank-returning) ∥ wsplit ∥ asplit
    p1_kernel<<<DEGB + WB + AB, 256, 0, stream>>>(ei, ew, pk_out, pk_in, rank,
                                                  W6, W7, Wp, Bsw, h5, Asw);

    scan1_kernel<<<SCAN_NB, 256, 0, stream>>>(pk_in, pk_out, deg_in, deg_out, partial);
    scan23_kernel<<<SCAN_NB, 256, 0, stream>>>(pk_in, partial, row_ptr);

    // fill (atomic-free) ∥ gemm layer-1 (swizzled f16 A)
    p2_kernel<<<FILLB + GB, 256, 0, stream>>>(ei, ew, rank, deg_out, deg_in, row_ptr,
                                              csr, Asw, Bsw, xt);

    agg_kernel<<<N_NODES / 8, 256, 0, stream>>>(xt, row_ptr, csr, b6, Asw);
    gemm_f16<0><<<GB, 256, 0, stream>>>(Asw, Bsw + 65536, nullptr, xt);
    agg_kernel<<<N_NODES / 8, 256, 0, stream>>>(xt, row_ptr, csr, b7, Asw);
    gemm_f16<1><<<GB, 256, 0, stream>>>(Asw, Bsw + 2 * 65536, bp, out);
}

// Round 16
// 146.086 us; speedup vs baseline: 1.1401x; 1.0986x over previous
//
#include <hip/hip_runtime.h>

#define N_NODES 50000
#define N_PANELS 3125            // 50000 / 16 exactly
#define N_EDGES 300000
#define EPS_F 1e-12f
#define DEGB 64                           // compact deg blocks (grid-stride)
#define ZB 98                             // zero blocks (400 KB / 4 KB)
#define WB 96                             // wsplit blocks
#define FILLB 128                         // fill blocks (grid-stride, atomic-free)
#define GB 512                            // gemm grid (grid-stride over panels)
#define SCAN_NB ((N_NODES + 255) / 256)   // 196
#define ZBYTES (N_NODES * 8)              // pk_out(4) + pk_in(4)

typedef _Float16 f16x8 __attribute__((ext_vector_type(8)));
typedef float f32x4 __attribute__((ext_vector_type(4)));

static __device__ inline f32x4 mfma_f16(f16x8 a, f16x8 b, f32x4 c) {
    return __builtin_amdgcn_mfma_f32_16x16x32_f16(a, b, c, 0, 0, 0);
}

// fragment-ready swizzled layout for a [R][256] f16 matrix (agg -> gemm path):
// element (row, k) at ((row>>4)*8 + (k>>5))*512 + ((k>>3)&3)*128 + (row&15)*8 + (k&7)
static __device__ inline size_t swz(int row, int l) {
    return ((size_t)(row >> 4) * 8 + (l >> 2)) * 512 + (size_t)((l & 3) * 128 + (row & 15) * 8);
}

// ---------------------------------------------------------------------------
// init: zero pk arrays ∥ wsplit (W -> swizzled f16 fragment layout)
// ---------------------------------------------------------------------------

__global__ __launch_bounds__(256) void init_kernel(int4* __restrict__ z,
                                                   const float* __restrict__ W6,
                                                   const float* __restrict__ W7,
                                                   const float* __restrict__ Wp,
                                                   _Float16* __restrict__ Bsw) {
    int b = blockIdx.x;
    if (b < ZB) {
        int i = b * 256 + threadIdx.x;
        if (i < ZBYTES / 16) z[i] = make_int4(0, 0, 0, 0);
    } else {
        int bb = b - ZB;                  // 0..95
        int wsel = bb >> 5;               // 0..2
        const float* W = (wsel == 0) ? W6 : (wsel == 1) ? W7 : Wp;
        int id = (bb & 31) * 256 + threadIdx.x;   // 0..8191
        int n = id >> 5, l = id & 31;
        f16x8 o;
#pragma unroll
        for (int j = 0; j < 8; ++j)
            o[j] = (_Float16)W[(l * 8 + j) * 256 + n];
        *(f16x8*)&Bsw[(size_t)wsel * 65536 + swz(n, l)] = o;
    }
}

// ---------------------------------------------------------------------------
// Phase A: deg (u32 packed atomics, rank-returning, compact 64 blocks)
//        ∥ fused asplit+gemm layer-1: per 16-row panel, coalesced f32 load ->
//          f16 LDS tile -> MFMA with register-resident W6 -> f16 row-major xt.
// Independent work; gemm hides under the atomic-throughput-bound deg.
// ---------------------------------------------------------------------------

__global__ __launch_bounds__(256) void pA_kernel(const int* __restrict__ ei,
                                                 const float* __restrict__ ew,
                                                 unsigned* __restrict__ pk_out,
                                                 unsigned* __restrict__ pk_in,
                                                 unsigned* __restrict__ rank,
                                                 const float* __restrict__ h5,
                                                 const _Float16* __restrict__ Bsw,
                                                 _Float16* __restrict__ xt) {
    __shared__ __align__(16) _Float16 atile[16 * 264];
    __shared__ __align__(16) _Float16 ebuf[4][16 * 72];

    int b = blockIdx.x;
    if (b < DEGB) {
        for (int e = b * 256 + (int)threadIdx.x; e < N_EDGES; e += DEGB * 256) {
            int s = ei[e];
            int d = ei[N_EDGES + e];
            unsigned wfx = (unsigned)(ew[e] * 262144.0f);   // 2^18
            atomicAdd(&pk_out[s], wfx);
            unsigned old = atomicAdd(&pk_in[d], (1u << 24) | wfx);
            rank[e] = old >> 24;
        }
        return;
    }

    const int t = threadIdx.x;
    const int w = t >> 6, lane = t & 63;
    const int srow = t >> 4;              // staging row 0..15
    const int scol = (t & 15) * 16;       // staging col base

    f16x8 bf[4][8];
#pragma unroll
    for (int cp4 = 0; cp4 < 4; ++cp4)
#pragma unroll
        for (int kb = 0; kb < 8; ++kb)
            bf[cp4][kb] = *(const f16x8*)&Bsw[(size_t)((w * 4 + cp4) * 8 + kb) * 512 + lane * 8];

    for (int p = b - DEGB; p < N_PANELS; p += GB) {
        // ---- stage: 16 rows x 256 f32, coalesced; convert to f16 LDS tile ----
        const float* src = &h5[(size_t)(p * 16 + srow) * 256 + scol];
        f16x8 c0, c1;
#pragma unroll
        for (int q = 0; q < 2; ++q) {
            float4 v0 = *(const float4*)(src + q * 8);
            float4 v1 = *(const float4*)(src + q * 8 + 4);
            f16x8& cc = q ? c1 : c0;
            cc[0] = (_Float16)v0.x; cc[1] = (_Float16)v0.y;
            cc[2] = (_Float16)v0.z; cc[3] = (_Float16)v0.w;
            cc[4] = (_Float16)v1.x; cc[5] = (_Float16)v1.y;
            cc[6] = (_Float16)v1.z; cc[7] = (_Float16)v1.w;
        }
        *(f16x8*)&atile[srow * 264 + scol] = c0;
        *(f16x8*)&atile[srow * 264 + scol + 8] = c1;
        __syncthreads();

        // ---- A-frags from LDS ----
        f16x8 af[8];
#pragma unroll
        for (int kb = 0; kb < 8; ++kb)
            af[kb] = *(const f16x8*)&atile[(lane & 15) * 264 + kb * 32 + (lane >> 4) * 8];
        __syncthreads();   // all reads done; atile reusable next panel

        f32x4 acc[4];
#pragma unroll
        for (int cp4 = 0; cp4 < 4; ++cp4) acc[cp4] = (f32x4){0.f, 0.f, 0.f, 0.f};
#pragma unroll
        for (int kb = 0; kb < 8; ++kb)
#pragma unroll
            for (int cp4 = 0; cp4 < 4; ++cp4)
                acc[cp4] = mfma_f16(af[kb], bf[cp4][kb], acc[cp4]);

        // D: row = 4*(lane>>4)+reg, col = lane&15  [m89-verified]
        _Float16* eb = ebuf[w];
        const int rq = 4 * (lane >> 4);
        const int lr = lane & 15;
#pragma unroll
        for (int cp4 = 0; cp4 < 4; ++cp4)
#pragma unroll
            for (int rr = 0; rr < 4; ++rr)
                eb[(rq + rr) * 72 + cp4 * 16 + lr] = (_Float16)acc[cp4][rr];
#pragma unroll
        for (int it = 0; it < 2; ++it) {
            int rl = it * 8 + (lane >> 3);
            f16x8 v = *(const f16x8*)&eb[rl * 72 + (lane & 7) * 8];
            *(f16x8*)&xt[(size_t)(p * 16 + rl) * 256 + w * 64 + (lane & 7) * 8] = v;
        }
    }
}

// --- scan: per-block reduce, then fused (partial-scan + local scan) ---------

__global__ __launch_bounds__(256) void scan1_kernel(const unsigned* __restrict__ pk_in,
                                                    const unsigned* __restrict__ pk_out,
                                                    float* __restrict__ deg_in,
                                                    float* __restrict__ deg_out,
                                                    int* __restrict__ partial) {
    __shared__ int sh[256];
    int i = blockIdx.x * 256 + threadIdx.x;
    int c = 0;
    if (i < N_NODES) {
        unsigned p = pk_in[i];
        c = (int)(p >> 24);
        deg_in[i] = (float)(p & 0xFFFFFFu) * 0x1p-18f;
        deg_out[i] = (float)pk_out[i] * 0x1p-18f;
    }
    sh[threadIdx.x] = c;
    __syncthreads();
    for (int off = 128; off > 0; off >>= 1) {
        if (threadIdx.x < (unsigned)off) sh[threadIdx.x] += sh[threadIdx.x + off];
        __syncthreads();
    }
    if (threadIdx.x == 0) partial[blockIdx.x] = sh[0];
}

// fused scan2+scan3: every block redundantly scans the 196 partials (trivial)
__global__ __launch_bounds__(256) void scan23_kernel(const unsigned* __restrict__ pk_in,
                                                     const int* __restrict__ partial,
                                                     int* __restrict__ row_ptr) {
    __shared__ int ps[256];
    __shared__ int sh[256];
    int t = threadIdx.x;
    int pv = (t < SCAN_NB) ? partial[t] : 0;
    ps[t] = pv;
    __syncthreads();
    for (int off = 1; off < 256; off <<= 1) {
        int x = (t >= off) ? ps[t - off] : 0;
        __syncthreads();
        ps[t] += x;
        __syncthreads();
    }
    int incl = ps[t];
    __syncthreads();
    ps[t] = incl - pv;    // exclusive prefix of partials
    __syncthreads();
    const int boff = ps[blockIdx.x];

    int i = blockIdx.x * 256 + t;
    int v = (i < N_NODES) ? (int)(pk_in[i] >> 24) : 0;
    sh[t] = v;
    __syncthreads();
    for (int off = 1; off < 256; off <<= 1) {
        int x = (t >= off) ? sh[t - off] : 0;
        __syncthreads();
        sh[t] += x;
        __syncthreads();
    }
    if (i < N_NODES) row_ptr[i] = sh[t] - v + boff;
    if (i == 0) row_ptr[N_NODES] = N_EDGES;
}

// ---------------------------------------------------------------------------
// fill: ATOMIC-FREE (slot = row_ptr[d] + rank[e]); fused norm.
// ---------------------------------------------------------------------------

__global__ __launch_bounds__(256) void fill_kernel(const int* __restrict__ ei,
                                                   const float* __restrict__ ew,
                                                   const unsigned* __restrict__ rank,
                                                   const float* __restrict__ deg_out,
                                                   const float* __restrict__ deg_in,
                                                   const int* __restrict__ row_ptr,
                                                   int2* __restrict__ csr) {
    for (int e = blockIdx.x * 256 + (int)threadIdx.x; e < N_EDGES; e += FILLB * 256) {
        int s = ei[e];
        int d = ei[N_EDGES + e];
        float nm = ew[e] * rsqrtf(deg_out[s] * deg_in[d] + EPS_F);
        csr[row_ptr[d] + (int)rank[e]] = make_int2(s, __float_as_int(nm));
    }
}

// ---------------------------------------------------------------------------
// gemm (swizzled f16 A): MODE 0 -> f16 row-major xt; MODE 1 -> f32 + bias out
// (MODE 1 epilogue bounces f32 through LDS for 256B-per-row coalesced stores)
// ---------------------------------------------------------------------------

template <int MODE>
__global__ __launch_bounds__(256) void gemm_f16(const _Float16* __restrict__ Asw,
                                                const _Float16* __restrict__ Bsw,
                                                const float* __restrict__ bias,
                                                void* __restrict__ Cout) {
    __shared__ __align__(16) char ebraw[4][16 * 68 * 4];   // fits f16x72 & f32x68

    const int t = threadIdx.x;
    const int w = t >> 6, lane = t & 63;
    const int lr = lane & 15;

    f16x8 bf[4][8];
#pragma unroll
    for (int cp4 = 0; cp4 < 4; ++cp4)
#pragma unroll
        for (int kb = 0; kb < 8; ++kb)
            bf[cp4][kb] = *(const f16x8*)&Bsw[(size_t)((w * 4 + cp4) * 8 + kb) * 512 + lane * 8];

    float bc[4];
    if (MODE == 1) {
#pragma unroll
        for (int cp4 = 0; cp4 < 4; ++cp4) bc[cp4] = bias[w * 64 + cp4 * 16 + lr];
    }

    for (int p = blockIdx.x; p < N_PANELS; p += GB) {
        const _Float16* abase = &Asw[(size_t)p * 4096 + lane * 8];
        f16x8 af[8];
#pragma unroll
        for (int kb = 0; kb < 8; ++kb)
            af[kb] = *(const f16x8*)&abase[kb * 512];

        f32x4 acc[4];
#pragma unroll
        for (int cp4 = 0; cp4 < 4; ++cp4) acc[cp4] = (f32x4){0.f, 0.f, 0.f, 0.f};
#pragma unroll
        for (int kb = 0; kb < 8; ++kb)
#pragma unroll
            for (int cp4 = 0; cp4 < 4; ++cp4)
                acc[cp4] = mfma_f16(af[kb], bf[cp4][kb], acc[cp4]);

        const int rq = 4 * (lane >> 4);
        if (MODE == 0) {
            _Float16* eb = (_Float16*)ebraw[w];
#pragma unroll
            for (int cp4 = 0; cp4 < 4; ++cp4)
#pragma unroll
                for (int rr = 0; rr < 4; ++rr)
                    eb[(rq + rr) * 72 + cp4 * 16 + lr] = (_Float16)acc[cp4][rr];
            _Float16* xp = (_Float16*)Cout;
#pragma unroll
            for (int it = 0; it < 2; ++it) {
                int rl = it * 8 + (lane >> 3);
                f16x8 v = *(const f16x8*)&eb[rl * 72 + (lane & 7) * 8];
                *(f16x8*)&xp[(size_t)(p * 16 + rl) * 256 + w * 64 + (lane & 7) * 8] = v;
            }
        } else {
            float* eb = (float*)ebraw[w];
#pragma unroll
            for (int cp4 = 0; cp4 < 4; ++cp4)
#pragma unroll
                for (int rr = 0; rr < 4; ++rr)
                    eb[(rq + rr) * 68 + cp4 * 16 + lr] = acc[cp4][rr] + bc[cp4];
            float* op = (float*)Cout;
#pragma unroll
            for (int it = 0; it < 4; ++it) {
                int rl = it * 4 + (lane >> 4);
                float4 v = *(const float4*)&eb[rl * 68 + lr * 4];
                *(float4*)&op[(size_t)(p * 16 + rl) * 256 + w * 64 + lr * 4] = v;
            }
        }
    }
}

// ---------------------------------------------------------------------------
// Aggregation: 8 nodes/block, 32 lanes/node, 8 features/lane, 4 gathers in
// flight; packed {src,norm} headers; writes fragment-swizzled f16 output.
// ---------------------------------------------------------------------------

__global__ __launch_bounds__(256) void agg_kernel(const _Float16* __restrict__ xt,
                                                  const int* __restrict__ row_ptr,
                                                  const int2* __restrict__ csr,
                                                  const float* __restrict__ bias,
                                                  _Float16* __restrict__ Asw) {
    const int g = threadIdx.x >> 5;
    const int l = threadIdx.x & 31;
    const int v = blockIdx.x * 8 + g;
    const int d0 = l * 8;

    const int s0 = row_ptr[v];
    const int s1 = row_ptr[v + 1];

    float acc[8] = {0.f, 0.f, 0.f, 0.f, 0.f, 0.f, 0.f, 0.f};

    int i = s0;
    for (; i + 4 <= s1; i += 4) {
        int2 hd[4];
#pragma unroll
        for (int u = 0; u < 4; ++u) hd[u] = csr[i + u];
        f16x8 val[4];
#pragma unroll
        for (int u = 0; u < 4; ++u)
            val[u] = *(const f16x8*)&xt[(size_t)hd[u].x * 256 + d0];
#pragma unroll
        for (int u = 0; u < 4; ++u) {
            float wv = __int_as_float(hd[u].y);
#pragma unroll
            for (int j = 0; j < 8; ++j)
                acc[j] += (float)val[u][j] * wv;
        }
    }
    {
        int rem = s1 - i;
        int2 hd[3];
#pragma unroll
        for (int u = 0; u < 3; ++u)
            hd[u] = (u < rem) ? csr[i + u] : make_int2(0, 0);
        f16x8 val[3];
#pragma unroll
        for (int u = 0; u < 3; ++u)
            val[u] = *(const f16x8*)&xt[(size_t)hd[u].x * 256 + d0];
#pragma unroll
        for (int u = 0; u < 3; ++u) {
            float wv = __int_as_float(hd[u].y);
#pragma unroll
            for (int j = 0; j < 8; ++j)
                acc[j] += (float)val[u][j] * wv;
        }
    }

    f16x8 o;
#pragma unroll
    for (int j = 0; j < 8; ++j) {
        float r = acc[j] + bias[d0 + j];
        r = r > 0.f ? r : 0.f;
        o[j] = (_Float16)r;
    }
    *(f16x8*)&Asw[swz(v, l)] = o;
}

// ---------------------------------------------------------------------------

extern "C" void kernel_launch(void* const* d_in, const int* in_sizes, int n_in,
                              void* d_out, int out_size, void* d_ws, size_t ws_size,
                              hipStream_t stream) {
    (void)in_sizes; (void)n_in; (void)out_size; (void)ws_size;
    const float* h5 = (const float*)d_in[0];
    const int*   ei = (const int*)d_in[1];
    const float* ew = (const float*)d_in[2];
    const float* W6 = (const float*)d_in[3];
    const float* b6 = (const float*)d_in[4];
    const float* W7 = (const float*)d_in[5];
    const float* b7 = (const float*)d_in[6];
    const float* Wp = (const float*)d_in[7];
    const float* bp = (const float*)d_in[8];
    float* out = (float*)d_out;

    char* ws = (char*)d_ws;
    size_t off = 0;
    auto alloc = [&](size_t bytes) -> void* {
        void* p = ws + off;
        off = (off + bytes + 255) & ~(size_t)255;
        return p;
    };

    // single zeroed region: pk_out | pk_in (u32)
    char* zblk = (char*)alloc(ZBYTES);
    unsigned* pk_out = (unsigned*)zblk;
    unsigned* pk_in  = (unsigned*)(zblk + N_NODES * 4);

    unsigned* rank  = (unsigned*)alloc(N_EDGES * 4);
    float* deg_out = (float*)alloc(N_NODES * 4);
    float* deg_in  = (float*)alloc(N_NODES * 4);
    int*   row_ptr = (int*)alloc((N_NODES + 1) * 4);
    int*   partial = (int*)alloc(SCAN_NB * 4);
    int2*  csr     = (int2*)alloc(N_EDGES * 8);
    _Float16* Bsw  = (_Float16*)alloc(3 * 65536 * 2);
    _Float16* Asw  = (_Float16*)alloc((size_t)N_NODES * 256 * 2);
    _Float16* xt   = (_Float16*)alloc((size_t)N_NODES * 256 * 2);

    // zero ∥ wsplit
    init_kernel<<<ZB + WB, 256, 0, stream>>>((int4*)zblk, W6, W7, Wp, Bsw);

    // deg (atomic-wall) ∥ fused asplit+gemm layer-1 (h5 f32 -> LDS f16 -> MFMA)
    pA_kernel<<<DEGB + GB, 256, 0, stream>>>(ei, ew, pk_out, pk_in, rank, h5, Bsw, xt);

    scan1_kernel<<<SCAN_NB, 256, 0, stream>>>(pk_in, pk_out, deg_in, deg_out, partial);
    scan23_kernel<<<SCAN_NB, 256, 0, stream>>>(pk_in, partial, row_ptr);

    // atomic-free fill
    fill_kernel<<<FILLB, 256, 0, stream>>>(ei, ew, rank, deg_out, deg_in, row_ptr, csr);

    agg_kernel<<<N_NODES / 8, 256, 0, stream>>>(xt, row_ptr, csr, b6, Asw);
    gemm_f16<0><<<GB, 256, 0, stream>>>(Asw, Bsw + 65536, nullptr, xt);
    agg_kernel<<<N_NODES / 8, 256, 0, stream>>>(xt, row_ptr, csr, b7, Asw);
    gemm_f16<1><<<GB, 256, 0, stream>>>(Asw, Bsw + 2 * 65536, bp, out);
}

// Round 17
// 143.700 us; speedup vs baseline: 1.1590x; 1.0166x over previous
//
#include <hip/hip_runtime.h>

#define N_NODES 50000
#define N_PANELS 3125            // 50000 / 16 exactly
#define N_EDGES 300000
#define EPS_F 1e-12f
#define DEGB 64                           // compact deg blocks (grid-stride)
#define ZB 98                             // zero blocks (400 KB / 4 KB)
#define WB 96                             // wsplit blocks
#define FILLB 256                         // fill blocks (grid-stride, atomic-free)
#define GB 512                            // gemm grid (grid-stride over panels)
#define SCAN_NB ((N_NODES + 255) / 256)   // 196
#define ZBYTES (N_NODES * 8)              // pk_out(4) + pk_in(4)

typedef _Float16 f16x8 __attribute__((ext_vector_type(8)));
typedef float f32x4 __attribute__((ext_vector_type(4)));

static __device__ inline f32x4 mfma_f16(f16x8 a, f16x8 b, f32x4 c) {
    return __builtin_amdgcn_mfma_f32_16x16x32_f16(a, b, c, 0, 0, 0);
}

// fragment-ready swizzled layout for a [R][256] f16 matrix (agg -> gemm path):
// element (row, k) at ((row>>4)*8 + (k>>5))*512 + ((k>>3)&3)*128 + (row&15)*8 + (k&7)
static __device__ inline size_t swz(int row, int l) {
    return ((size_t)(row >> 4) * 8 + (l >> 2)) * 512 + (size_t)((l & 3) * 128 + (row & 15) * 8);
}

// ---------------------------------------------------------------------------
// init: zero pk arrays ∥ wsplit (W -> swizzled f16 fragment layout)
// ---------------------------------------------------------------------------

__global__ __launch_bounds__(256) void init_kernel(int4* __restrict__ z,
                                                   const float* __restrict__ W6,
                                                   const float* __restrict__ W7,
                                                   const float* __restrict__ Wp,
                                                   _Float16* __restrict__ Bsw) {
    int b = blockIdx.x;
    if (b < ZB) {
        int i = b * 256 + threadIdx.x;
        if (i < ZBYTES / 16) z[i] = make_int4(0, 0, 0, 0);
    } else {
        int bb = b - ZB;                  // 0..95
        int wsel = bb >> 5;               // 0..2
        const float* W = (wsel == 0) ? W6 : (wsel == 1) ? W7 : Wp;
        int id = (bb & 31) * 256 + threadIdx.x;   // 0..8191
        int n = id >> 5, l = id & 31;
        f16x8 o;
#pragma unroll
        for (int j = 0; j < 8; ++j)
            o[j] = (_Float16)W[(l * 8 + j) * 256 + n];
        *(f16x8*)&Bsw[(size_t)wsel * 65536 + swz(n, l)] = o;
    }
}

// ---------------------------------------------------------------------------
// Phase A: deg (u32 packed atomics, rank-returning, compact 64 blocks)
//        ∥ fused asplit+gemm layer-1: per 16-row panel, coalesced f32 load ->
//          f16 LDS tile -> MFMA with register-resident W6 -> f16 row-major xt.
// ---------------------------------------------------------------------------

__global__ __launch_bounds__(256) void pA_kernel(const int* __restrict__ ei,
                                                 const float* __restrict__ ew,
                                                 unsigned* __restrict__ pk_out,
                                                 unsigned* __restrict__ pk_in,
                                                 unsigned* __restrict__ rank,
                                                 const float* __restrict__ h5,
                                                 const _Float16* __restrict__ Bsw,
                                                 _Float16* __restrict__ xt) {
    __shared__ __align__(16) _Float16 atile[16 * 264];
    __shared__ __align__(16) _Float16 ebuf[4][16 * 72];

    int b = blockIdx.x;
    if (b < DEGB) {
        for (int e = b * 256 + (int)threadIdx.x; e < N_EDGES; e += DEGB * 256) {
            int s = ei[e];
            int d = ei[N_EDGES + e];
            unsigned wfx = (unsigned)(ew[e] * 262144.0f);   // 2^18
            atomicAdd(&pk_out[s], wfx);
            unsigned old = atomicAdd(&pk_in[d], (1u << 24) | wfx);
            rank[e] = old >> 24;
        }
        return;
    }

    const int t = threadIdx.x;
    const int w = t >> 6, lane = t & 63;
    const int srow = t >> 4;              // staging row 0..15
    const int scol = (t & 15) * 16;       // staging col base

    f16x8 bf[4][8];
#pragma unroll
    for (int cp4 = 0; cp4 < 4; ++cp4)
#pragma unroll
        for (int kb = 0; kb < 8; ++kb)
            bf[cp4][kb] = *(const f16x8*)&Bsw[(size_t)((w * 4 + cp4) * 8 + kb) * 512 + lane * 8];

    for (int p = b - DEGB; p < N_PANELS; p += GB) {
        // ---- stage: 16 rows x 256 f32, coalesced; convert to f16 LDS tile ----
        const float* src = &h5[(size_t)(p * 16 + srow) * 256 + scol];
        f16x8 c0, c1;
#pragma unroll
        for (int q = 0; q < 2; ++q) {
            float4 v0 = *(const float4*)(src + q * 8);
            float4 v1 = *(const float4*)(src + q * 8 + 4);
            f16x8& cc = q ? c1 : c0;
            cc[0] = (_Float16)v0.x; cc[1] = (_Float16)v0.y;
            cc[2] = (_Float16)v0.z; cc[3] = (_Float16)v0.w;
            cc[4] = (_Float16)v1.x; cc[5] = (_Float16)v1.y;
            cc[6] = (_Float16)v1.z; cc[7] = (_Float16)v1.w;
        }
        *(f16x8*)&atile[srow * 264 + scol] = c0;
        *(f16x8*)&atile[srow * 264 + scol + 8] = c1;
        __syncthreads();

        // ---- A-frags from LDS ----
        f16x8 af[8];
#pragma unroll
        for (int kb = 0; kb < 8; ++kb)
            af[kb] = *(const f16x8*)&atile[(lane & 15) * 264 + kb * 32 + (lane >> 4) * 8];
        __syncthreads();   // all reads done; atile reusable next panel

        f32x4 acc[4];
#pragma unroll
        for (int cp4 = 0; cp4 < 4; ++cp4) acc[cp4] = (f32x4){0.f, 0.f, 0.f, 0.f};
#pragma unroll
        for (int kb = 0; kb < 8; ++kb)
#pragma unroll
            for (int cp4 = 0; cp4 < 4; ++cp4)
                acc[cp4] = mfma_f16(af[kb], bf[cp4][kb], acc[cp4]);

        // D: row = 4*(lane>>4)+reg, col = lane&15  [m89-verified]
        _Float16* eb = ebuf[w];
        const int rq = 4 * (lane >> 4);
        const int lr = lane & 15;
#pragma unroll
        for (int cp4 = 0; cp4 < 4; ++cp4)
#pragma unroll
            for (int rr = 0; rr < 4; ++rr)
                eb[(rq + rr) * 72 + cp4 * 16 + lr] = (_Float16)acc[cp4][rr];
#pragma unroll
        for (int it = 0; it < 2; ++it) {
            int rl = it * 8 + (lane >> 3);
            f16x8 v = *(const f16x8*)&eb[rl * 72 + (lane & 7) * 8];
            *(f16x8*)&xt[(size_t)(p * 16 + rl) * 256 + w * 64 + (lane & 7) * 8] = v;
        }
    }
}

// --- scan: per-block reduce, then fused (partial-scan + local scan) ---------

__global__ __launch_bounds__(256) void scan1_kernel(const unsigned* __restrict__ pk_in,
                                                    const unsigned* __restrict__ pk_out,
                                                    float* __restrict__ deg_in,
                                                    float* __restrict__ deg_out,
                                                    int* __restrict__ partial) {
    __shared__ int sh[256];
    int i = blockIdx.x * 256 + threadIdx.x;
    int c = 0;
    if (i < N_NODES) {
        unsigned p = pk_in[i];
        c = (int)(p >> 24);
        deg_in[i] = (float)(p & 0xFFFFFFu) * 0x1p-18f;
        deg_out[i] = (float)pk_out[i] * 0x1p-18f;
    }
    sh[threadIdx.x] = c;
    __syncthreads();
    for (int off = 128; off > 0; off >>= 1) {
        if (threadIdx.x < (unsigned)off) sh[threadIdx.x] += sh[threadIdx.x + off];
        __syncthreads();
    }
    if (threadIdx.x == 0) partial[blockIdx.x] = sh[0];
}

// fused scan2+scan3: every block redundantly scans the 196 partials (trivial)
__global__ __launch_bounds__(256) void scan23_kernel(const unsigned* __restrict__ pk_in,
                                                     const int* __restrict__ partial,
                                                     int* __restrict__ row_ptr) {
    __shared__ int ps[256];
    __shared__ int sh[256];
    int t = threadIdx.x;
    int pv = (t < SCAN_NB) ? partial[t] : 0;
    ps[t] = pv;
    __syncthreads();
    for (int off = 1; off < 256; off <<= 1) {
        int x = (t >= off) ? ps[t - off] : 0;
        __syncthreads();
        ps[t] += x;
        __syncthreads();
    }
    int incl = ps[t];
    __syncthreads();
    ps[t] = incl - pv;    // exclusive prefix of partials
    __syncthreads();
    const int boff = ps[blockIdx.x];

    int i = blockIdx.x * 256 + t;
    int v = (i < N_NODES) ? (int)(pk_in[i] >> 24) : 0;
    sh[t] = v;
    __syncthreads();
    for (int off = 1; off < 256; off <<= 1) {
        int x = (t >= off) ? sh[t - off] : 0;
        __syncthreads();
        sh[t] += x;
        __syncthreads();
    }
    if (i < N_NODES) row_ptr[i] = sh[t] - v + boff;
    if (i == 0) row_ptr[N_NODES] = N_EDGES;
}

// ---------------------------------------------------------------------------
// fill: ATOMIC-FREE (slot = row_ptr[d] + rank[e]); fused norm.
// ---------------------------------------------------------------------------

__global__ __launch_bounds__(256) void fill_kernel(const int* __restrict__ ei,
                                                   const float* __restrict__ ew,
                                                   const unsigned* __restrict__ rank,
                                                   const float* __restrict__ deg_out,
                                                   const float* __restrict__ deg_in,
                                                   const int* __restrict__ row_ptr,
                                                   int2* __restrict__ csr) {
    for (int e = blockIdx.x * 256 + (int)threadIdx.x; e < N_EDGES; e += FILLB * 256) {
        int s = ei[e];
        int d = ei[N_EDGES + e];
        float nm = ew[e] * rsqrtf(deg_out[s] * deg_in[d] + EPS_F);
        csr[row_ptr[d] + (int)rank[e]] = make_int2(s, __float_as_int(nm));
    }
}

// ---------------------------------------------------------------------------
// gemm (swizzled f16 A): MODE 0 -> f16 row-major xt; MODE 1 -> f32 + bias out
// ---------------------------------------------------------------------------

template <int MODE>
__global__ __launch_bounds__(256) void gemm_f16(const _Float16* __restrict__ Asw,
                                                const _Float16* __restrict__ Bsw,
                                                const float* __restrict__ bias,
                                                void* __restrict__ Cout) {
    __shared__ __align__(16) char ebraw[4][16 * 68 * 4];   // fits f16x72 & f32x68

    const int t = threadIdx.x;
    const int w = t >> 6, lane = t & 63;
    const int lr = lane & 15;

    f16x8 bf[4][8];
#pragma unroll
    for (int cp4 = 0; cp4 < 4; ++cp4)
#pragma unroll
        for (int kb = 0; kb < 8; ++kb)
            bf[cp4][kb] = *(const f16x8*)&Bsw[(size_t)((w * 4 + cp4) * 8 + kb) * 512 + lane * 8];

    float bc[4];
    if (MODE == 1) {
#pragma unroll
        for (int cp4 = 0; cp4 < 4; ++cp4) bc[cp4] = bias[w * 64 + cp4 * 16 + lr];
    }

    for (int p = blockIdx.x; p < N_PANELS; p += GB) {
        const _Float16* abase = &Asw[(size_t)p * 4096 + lane * 8];
        f16x8 af[8];
#pragma unroll
        for (int kb = 0; kb < 8; ++kb)
            af[kb] = *(const f16x8*)&abase[kb * 512];

        f32x4 acc[4];
#pragma unroll
        for (int cp4 = 0; cp4 < 4; ++cp4) acc[cp4] = (f32x4){0.f, 0.f, 0.f, 0.f};
#pragma unroll
        for (int kb = 0; kb < 8; ++kb)
#pragma unroll
            for (int cp4 = 0; cp4 < 4; ++cp4)
                acc[cp4] = mfma_f16(af[kb], bf[cp4][kb], acc[cp4]);

        const int rq = 4 * (lane >> 4);
        if (MODE == 0) {
            _Float16* eb = (_Float16*)ebraw[w];
#pragma unroll
            for (int cp4 = 0; cp4 < 4; ++cp4)
#pragma unroll
                for (int rr = 0; rr < 4; ++rr)
                    eb[(rq + rr) * 72 + cp4 * 16 + lr] = (_Float16)acc[cp4][rr];
            _Float16* xp = (_Float16*)Cout;
#pragma unroll
            for (int it = 0; it < 2; ++it) {
                int rl = it * 8 + (lane >> 3);
                f16x8 v = *(const f16x8*)&eb[rl * 72 + (lane & 7) * 8];
                *(f16x8*)&xp[(size_t)(p * 16 + rl) * 256 + w * 64 + (lane & 7) * 8] = v;
            }
        } else {
            float* eb = (float*)ebraw[w];
#pragma unroll
            for (int cp4 = 0; cp4 < 4; ++cp4)
#pragma unroll
                for (int rr = 0; rr < 4; ++rr)
                    eb[(rq + rr) * 68 + cp4 * 16 + lr] = acc[cp4][rr] + bc[cp4];
            float* op = (float*)Cout;
#pragma unroll
            for (int it = 0; it < 4; ++it) {
                int rl = it * 4 + (lane >> 4);
                float4 v = *(const float4*)&eb[rl * 68 + lr * 4];
                *(float4*)&op[(size_t)(p * 16 + rl) * 256 + w * 64 + lr * 4] = v;
            }
        }
    }
}

// ---------------------------------------------------------------------------
// Aggregation v3: 16 nodes/block, 16 lanes/node, 16 features/lane (2x f16x8),
// 4-edge batches -> 8 row-chunk loads in flight per lane (2x round-16 MLP).
// Same per-feature f32 accumulation order as before (identical rounding).
// ---------------------------------------------------------------------------

__global__ __launch_bounds__(256) void agg_kernel(const _Float16* __restrict__ xt,
                                                  const int* __restrict__ row_ptr,
                                                  const int2* __restrict__ csr,
                                                  const float* __restrict__ bias,
                                                  _Float16* __restrict__ Asw) {
    const int g = threadIdx.x >> 4;           // node slot 0..15
    const int l = threadIdx.x & 15;           // lane within node group
    const int v = blockIdx.x * 16 + g;
    const int d0 = l * 16;                    // this lane's 16 features

    const int s0 = row_ptr[v];
    const int s1 = row_ptr[v + 1];

    float acc[16];
#pragma unroll
    for (int j = 0; j < 16; ++j) acc[j] = 0.f;

    int i = s0;
    for (; i + 4 <= s1; i += 4) {
        int2 hd[4];
#pragma unroll
        for (int u = 0; u < 4; ++u) hd[u] = csr[i + u];
        f16x8 va[4], vb[4];
#pragma unroll
        for (int u = 0; u < 4; ++u) {
            const _Float16* rp = &xt[(size_t)hd[u].x * 256 + d0];
            va[u] = *(const f16x8*)rp;
            vb[u] = *(const f16x8*)(rp + 8);
        }
#pragma unroll
        for (int u = 0; u < 4; ++u) {
            float wv = __int_as_float(hd[u].y);
#pragma unroll
            for (int j = 0; j < 8; ++j) {
                acc[j]     += (float)va[u][j] * wv;
                acc[8 + j] += (float)vb[u][j] * wv;
            }
        }
    }
    {
        int rem = s1 - i;   // 0..3
        int2 hd[3];
#pragma unroll
        for (int u = 0; u < 3; ++u)
            hd[u] = (u < rem) ? csr[i + u] : make_int2(0, 0);
        f16x8 va[3], vb[3];
#pragma unroll
        for (int u = 0; u < 3; ++u) {
            const _Float16* rp = &xt[(size_t)hd[u].x * 256 + d0];
            va[u] = *(const f16x8*)rp;
            vb[u] = *(const f16x8*)(rp + 8);
        }
#pragma unroll
        for (int u = 0; u < 3; ++u) {
            float wv = __int_as_float(hd[u].y);
#pragma unroll
            for (int j = 0; j < 8; ++j) {
                acc[j]     += (float)va[u][j] * wv;
                acc[8 + j] += (float)vb[u][j] * wv;
            }
        }
    }

    f16x8 o0, o1;
#pragma unroll
    for (int j = 0; j < 8; ++j) {
        float r0 = acc[j] + bias[d0 + j];
        float r1 = acc[8 + j] + bias[d0 + 8 + j];
        r0 = r0 > 0.f ? r0 : 0.f;
        r1 = r1 > 0.f ? r1 : 0.f;
        o0[j] = (_Float16)r0;
        o1[j] = (_Float16)r1;
    }
    *(f16x8*)&Asw[swz(v, 2 * l)] = o0;
    *(f16x8*)&Asw[swz(v, 2 * l + 1)] = o1;
}

// ---------------------------------------------------------------------------

extern "C" void kernel_launch(void* const* d_in, const int* in_sizes, int n_in,
                              void* d_out, int out_size, void* d_ws, size_t ws_size,
                              hipStream_t stream) {
    (void)in_sizes; (void)n_in; (void)out_size; (void)ws_size;
    const float* h5 = (const float*)d_in[0];
    const int*   ei = (const int*)d_in[1];
    const float* ew = (const float*)d_in[2];
    const float* W6 = (const float*)d_in[3];
    const float* b6 = (const float*)d_in[4];
    const float* W7 = (const float*)d_in[5];
    const float* b7 = (const float*)d_in[6];
    const float* Wp = (const float*)d_in[7];
    const float* bp = (const float*)d_in[8];
    float* out = (float*)d_out;

    char* ws = (char*)d_ws;
    size_t off = 0;
    auto alloc = [&](size_t bytes) -> void* {
        void* p = ws + off;
        off = (off + bytes + 255) & ~(size_t)255;
        return p;
    };

    // single zeroed region: pk_out | pk_in (u32)
    char* zblk = (char*)alloc(ZBYTES);
    unsigned* pk_out = (unsigned*)zblk;
    unsigned* pk_in  = (unsigned*)(zblk + N_NODES * 4);

    unsigned* rank  = (unsigned*)alloc(N_EDGES * 4);
    float* deg_out = (float*)alloc(N_NODES * 4);
    float* deg_in  = (float*)alloc(N_NODES * 4);
    int*   row_ptr = (int*)alloc((N_NODES + 1) * 4);
    int*   partial = (int*)alloc(SCAN_NB * 4);
    int2*  csr     = (int2*)alloc(N_EDGES * 8);
    _Float16* Bsw  = (_Float16*)alloc(3 * 65536 * 2);
    _Float16* Asw  = (_Float16*)alloc((size_t)N_NODES * 256 * 2);
    _Float16* xt   = (_Float16*)alloc((size_t)N_NODES * 256 * 2);

    // zero ∥ wsplit
    init_kernel<<<ZB + WB, 256, 0, stream>>>((int4*)zblk, W6, W7, Wp, Bsw);

    // deg (atomic-wall) ∥ fused asplit+gemm layer-1
    pA_kernel<<<DEGB + GB, 256, 0, stream>>>(ei, ew, pk_out, pk_in, rank, h5, Bsw, xt);

    scan1_kernel<<<SCAN_NB, 256, 0, stream>>>(pk_in, pk_out, deg_in, deg_out, partial);
    scan23_kernel<<<SCAN_NB, 256, 0, stream>>>(pk_in, partial, row_ptr);

    // atomic-free fill
    fill_kernel<<<FILLB, 256, 0, stream>>>(ei, ew, rank, deg_out, deg_in, row_ptr, csr);

    agg_kernel<<<N_NODES / 16, 256, 0, stream>>>(xt, row_ptr, csr, b6, Asw);
    gemm_f16<0><<<GB, 256, 0, stream>>>(Asw, Bsw + 65536, nullptr, xt);
    agg_kernel<<<N_NODES / 16, 256, 0, stream>>>(xt, row_ptr, csr, b7, Asw);
    gemm_f16<1><<<GB, 256, 0, stream>>>(Asw, Bsw + 2 * 65536, bp, out);
}